// Round 6
// baseline (441.377 us; speedup 1.0000x reference)
//
#include <hip/hip_runtime.h>
#include <hip/hip_bf16.h>
#include <math.h>

#define DMODEL 1024
#define NH 16
#define HD 64
#define SEQ 2048
#define BATCH 2
#define MROWS (BATCH * SEQ)   // 4096
#define FFN_DIM 4096

using bf16x8 = __attribute__((ext_vector_type(8))) __bf16;
using f32x4  = __attribute__((ext_vector_type(4))) float;

typedef const __attribute__((address_space(1))) unsigned char* gas_t;
typedef __attribute__((address_space(3))) unsigned char* las_t;

__device__ inline unsigned short f2bf(float f) {
    unsigned int u = __builtin_bit_cast(unsigned int, f);
    u += 0x7fffu + ((u >> 16) & 1u);   // round-to-nearest-even
    return (unsigned short)(u >> 16);
}
// round-half-up — fine for positive P in (0,1]; 2 VALU ops instead of 4
__device__ inline unsigned short f2bf_up(float f) {
    unsigned int u = __builtin_bit_cast(unsigned int, f);
    return (unsigned short)((u + 0x8000u) >> 16);
}
__device__ inline float bf2f(unsigned short u) {
    unsigned int v = ((unsigned int)u) << 16;
    return __builtin_bit_cast(float, v);
}

// ---------------- fp32 -> bf16 conversion (weights) ----------------
__global__ void cvt_f32_bf16(const float* __restrict__ in,
                             unsigned short* __restrict__ out, int n4) {
    int i = blockIdx.x * blockDim.x + threadIdx.x;
    if (i < n4) {
        float4 v = ((const float4*)in)[i];
        ushort4 o;
        o.x = f2bf(v.x); o.y = f2bf(v.y); o.z = f2bf(v.z); o.w = f2bf(v.w);
        ((ushort4*)out)[i] = o;
    }
}

// ---------------- fused (residual-add +) LayerNorm ----------------
__global__ __launch_bounds__(256) void ln_fused(
        const float* __restrict__ a, const float* __restrict__ b,
        const float* __restrict__ gamma, const float* __restrict__ beta,
        float* __restrict__ out_f, unsigned short* __restrict__ out_b) {
    int row = blockIdx.x;
    int t = threadIdx.x;
    float4 v = ((const float4*)(a + (size_t)row * DMODEL))[t];
    if (b) {
        float4 w = ((const float4*)(b + (size_t)row * DMODEL))[t];
        v.x += w.x; v.y += w.y; v.z += w.z; v.w += w.w;
    }
    float s  = v.x + v.y + v.z + v.w;
    float s2 = v.x * v.x + v.y * v.y + v.z * v.z + v.w * v.w;
    #pragma unroll
    for (int off = 32; off > 0; off >>= 1) {
        s  += __shfl_xor(s,  off, 64);
        s2 += __shfl_xor(s2, off, 64);
    }
    __shared__ float red[8];
    int wave = t >> 6, lane = t & 63;
    if (lane == 0) { red[wave] = s; red[4 + wave] = s2; }
    __syncthreads();
    float tot  = red[0] + red[1] + red[2] + red[3];
    float tot2 = red[4] + red[5] + red[6] + red[7];
    float mu   = tot * (1.0f / DMODEL);
    float var  = tot2 * (1.0f / DMODEL) - mu * mu;
    float rstd = rsqrtf(var + 1e-5f);
    float4 g  = ((const float4*)gamma)[t];
    float4 be = ((const float4*)beta)[t];
    float4 o;
    o.x = (v.x - mu) * rstd * g.x + be.x;
    o.y = (v.y - mu) * rstd * g.y + be.y;
    o.z = (v.z - mu) * rstd * g.z + be.z;
    o.w = (v.w - mu) * rstd * g.w + be.w;
    if (out_f) ((float4*)(out_f + (size_t)row * DMODEL))[t] = o;
    if (out_b) {
        ushort4 ob;
        ob.x = f2bf(o.x); ob.y = f2bf(o.y); ob.z = f2bf(o.z); ob.w = f2bf(o.w);
        ((ushort4*)(out_b + (size_t)row * DMODEL))[t] = ob;
    }
}

// ---------------- AddNorm fused with split-K reduction (FC2 epilogue) ----------------
__global__ __launch_bounds__(256) void ln_fc2(
        const float* __restrict__ p0, const float* __restrict__ p1,
        const float* __restrict__ p2, const float* __restrict__ p3,
        const float* __restrict__ bias, const float* __restrict__ resid,
        const float* __restrict__ gamma, const float* __restrict__ beta,
        float* __restrict__ out_f) {
    int row = blockIdx.x;
    int t = threadIdx.x;
    size_t base = (size_t)row * DMODEL;
    float4 v  = ((const float4*)(p0 + base))[t];
    float4 w1 = ((const float4*)(p1 + base))[t];
    float4 w2 = ((const float4*)(p2 + base))[t];
    float4 w3 = ((const float4*)(p3 + base))[t];
    float4 bb = ((const float4*)bias)[t];
    float4 rr = ((const float4*)(resid + base))[t];
    v.x += w1.x + w2.x + w3.x + bb.x + rr.x;
    v.y += w1.y + w2.y + w3.y + bb.y + rr.y;
    v.z += w1.z + w2.z + w3.z + bb.z + rr.z;
    v.w += w1.w + w2.w + w3.w + bb.w + rr.w;

    float s  = v.x + v.y + v.z + v.w;
    float s2 = v.x * v.x + v.y * v.y + v.z * v.z + v.w * v.w;
    #pragma unroll
    for (int off = 32; off > 0; off >>= 1) {
        s  += __shfl_xor(s,  off, 64);
        s2 += __shfl_xor(s2, off, 64);
    }
    __shared__ float red[8];
    int wave = t >> 6, lane = t & 63;
    if (lane == 0) { red[wave] = s; red[4 + wave] = s2; }
    __syncthreads();
    float tot  = red[0] + red[1] + red[2] + red[3];
    float tot2 = red[4] + red[5] + red[6] + red[7];
    float mu   = tot * (1.0f / DMODEL);
    float var  = tot2 * (1.0f / DMODEL) - mu * mu;
    float rstd = rsqrtf(var + 1e-5f);
    float4 g  = ((const float4*)gamma)[t];
    float4 be = ((const float4*)beta)[t];
    float4 o;
    o.x = (v.x - mu) * rstd * g.x + be.x;
    o.y = (v.y - mu) * rstd * g.y + be.y;
    o.z = (v.z - mu) * rstd * g.z + be.z;
    o.w = (v.w - mu) * rstd * g.w + be.w;
    ((float4*)(out_f + base))[t] = o;
}

// ---------------- m97-style LDS-staged bf16 NT GEMM ----------------
// MODE 1: bias+GELU->bf16  MODE 2: bias->f32  MODE 3: qkv scatter bf16
// MODE 4: split-K fp32 partial (no bias)
template <int MODE>
__global__ __launch_bounds__(256) void gemm_lds(
        const unsigned short* __restrict__ A,
        const unsigned short* __restrict__ Bw,
        const float* __restrict__ bias,
        void* __restrict__ out, float* __restrict__ q1,
        float* __restrict__ q2, float* __restrict__ q3,
        int M, int N, int K, int KC) {
    __shared__ unsigned short As[128 * 32];
    __shared__ unsigned short Bs[128 * 32];

    const int tid  = threadIdx.x;
    const int wave = tid >> 6;
    const int lane = tid & 63;
    const int quad = lane >> 4;
    const int cc   = lane & 15;
    const int bn = blockIdx.x * 128;
    const int bm = blockIdx.y * 128;

    const unsigned short* Ab = A  + (size_t)bm * K;
    const unsigned short* Bb = Bw + (size_t)bn * K;

    const int srow0 = tid >> 2;
    const int ssg   = tid & 3;
    const int rsg = quad ^ ((cc >> 1) & 3);
    const int wm = (wave >> 1) * 64;
    const int wn = (wave & 1) * 64;

    const int kbeg = blockIdx.z * KC;
    const int kend = kbeg + KC;

    f32x4 acc[4][4] = {};

    for (int k0 = kbeg; k0 < kend; k0 += 32) {
        #pragma unroll
        for (int i = 0; i < 2; ++i) {
            int row = i * 64 + srow0;
            int g   = ssg ^ ((row >> 1) & 3);
            const unsigned short* ga = Ab + (size_t)row * K + k0 + g * 8;
            const unsigned short* gb = Bb + (size_t)row * K + k0 + g * 8;
            unsigned short* la = &As[i * 2048 + wave * 512];
            unsigned short* lb = &Bs[i * 2048 + wave * 512];
            __builtin_amdgcn_global_load_lds((gas_t)(const void*)ga, (las_t)(void*)la, 16, 0, 0);
            __builtin_amdgcn_global_load_lds((gas_t)(const void*)gb, (las_t)(void*)lb, 16, 0, 0);
        }
        __syncthreads();

        bf16x8 af[4], bf[4];
        #pragma unroll
        for (int mt = 0; mt < 4; ++mt)
            af[mt] = *(const bf16x8*)&As[(wm + mt * 16 + cc) * 32 + rsg * 8];
        #pragma unroll
        for (int nt = 0; nt < 4; ++nt)
            bf[nt] = *(const bf16x8*)&Bs[(wn + nt * 16 + cc) * 32 + rsg * 8];

        #pragma unroll
        for (int mt = 0; mt < 4; ++mt)
            #pragma unroll
            for (int nt = 0; nt < 4; ++nt)
                acc[mt][nt] = __builtin_amdgcn_mfma_f32_16x16x32_bf16(
                    af[mt], bf[nt], acc[mt][nt], 0, 0, 0);

        __syncthreads();
    }

    float* outp = (float*)out;
    if constexpr (MODE == 4) {
        outp = (blockIdx.z == 0) ? (float*)out
             : (blockIdx.z == 1) ? q1
             : (blockIdx.z == 2) ? q2 : q3;
    }

    #pragma unroll
    for (int mt = 0; mt < 4; ++mt)
        #pragma unroll
        for (int nt = 0; nt < 4; ++nt)
            #pragma unroll
            for (int r = 0; r < 4; ++r) {
                int m = bm + wm + mt * 16 + quad * 4 + r;
                int n = bn + wn + nt * 16 + cc;
                if constexpr (MODE == 4) {
                    outp[(size_t)m * N + n] = acc[mt][nt][r];
                    continue;
                }
                float v = acc[mt][nt][r] + bias[n];
                if constexpr (MODE == 1)
                    v = 0.5f * v * (1.0f + erff(v * 0.70710678118654752f));
                if constexpr (MODE == 2) {
                    ((float*)out)[(size_t)m * N + n] = v;
                } else if constexpr (MODE == 3) {
                    int b_ = m >> 11, srow = m & 2047;
                    int which = n >> 10, rem = n & 1023;
                    int h = rem >> 6, d = rem & 63;
                    size_t idx = ((((size_t)which * BATCH + b_) * NH + h) * SEQ + srow) * HD + d;
                    ((unsigned short*)out)[idx] = f2bf(v);
                } else {
                    ((unsigned short*)out)[(size_t)m * N + n] = f2bf(v);
                }
            }
}

// ---------------- V transpose: [bh][s][hd] -> [bh][hd][s] ----------------
__global__ __launch_bounds__(256) void transpose_v(
        const unsigned short* __restrict__ vsrc, unsigned short* __restrict__ vt) {
    __shared__ unsigned short Ls[64 * 72];
    const int t = threadIdx.x;
    const int s0 = blockIdx.x * 64;
    const int bh = blockIdx.y;
    const unsigned short* in = vsrc + (size_t)bh * SEQ * HD;
    unsigned short* outp = vt + (size_t)bh * SEQ * HD;

    const int row = t >> 2;
    const int c8  = (t & 3) * 8;
    #pragma unroll
    for (int p = 0; p < 2; ++p)
        *(uint4*)&Ls[row * 72 + c8 + p * 32] =
            *(const uint4*)&in[(size_t)(s0 + row) * HD + c8 + p * 32];
    __syncthreads();

    const int hd = t >> 2;
    #pragma unroll
    for (int p = 0; p < 2; ++p) {
        unsigned short tmp[8];
        #pragma unroll
        for (int j = 0; j < 8; ++j)
            tmp[j] = Ls[(c8 + p * 32 + j) * 72 + hd];
        *(uint4*)&outp[(size_t)hd * SEQ + s0 + c8 + p * 32] = *(uint4*)tmp;
    }
}

// ---------------- MFMA flash attention v3 ----------------
// Software-pipelined: register prefetch of tile kt+1 issued right after the
// single per-tile barrier; K/V LDS double-buffered -> loads fly during compute.
#define KPAD 72
#define TILE_ELEMS (64 * KPAD)
__global__ __launch_bounds__(256) void attn_mfma(
        const unsigned short* __restrict__ qkv,
        const unsigned short* __restrict__ vt, float* __restrict__ attn_out) {
    const int tid  = threadIdx.x;
    const int wave = tid >> 6;
    const int lane = tid & 63;
    const int quad = lane >> 4;
    const int cc   = lane & 15;
    const int qblk = blockIdx.x;
    const int bh   = blockIdx.y;

    const size_t headsz = (size_t)SEQ * HD;
    const unsigned short* qb  = qkv + (size_t)bh * headsz;
    const unsigned short* kb  = qkv + ((size_t)BATCH * NH + bh) * headsz;
    const unsigned short* vtb = vt + (size_t)bh * headsz;

    __shared__ unsigned short Ks[2 * TILE_ELEMS];   // K tiles [key][hd], dbuf
    __shared__ unsigned short Vt[2 * TILE_ELEMS];   // V^T tiles [hd][key], dbuf
    __shared__ unsigned short Ps[4 * 16 * KPAD];    // per-wave P [qrow][key]

    const int qrow = qblk * 64 + wave * 16 + cc;
    const unsigned short* qp = qb + (size_t)qrow * HD + quad * 8;
    bf16x8 qa0 = *(const bf16x8*)qp;
    bf16x8 qa1 = *(const bf16x8*)(qp + 32);

    f32x4 o_acc[4] = {};
    float l_i[4] = {0.f, 0.f, 0.f, 0.f};

    // staging: per wave, row = wave*16 + (lane>>2), col = (lane&3)*8 + p*32
    const int srow = wave * 16 + (lane >> 2);
    const int sc8  = (lane & 3) * 8;

    uint4 kreg[2], vreg[2];
    #pragma unroll
    for (int p = 0; p < 2; ++p) {
        int col = sc8 + p * 32;
        kreg[p] = *(const uint4*)&kb[(size_t)srow * HD + col];
        vreg[p] = *(const uint4*)&vtb[(size_t)srow * SEQ + col];
    }

    for (int kt = 0; kt < SEQ / 64; ++kt) {
        const int buf = (kt & 1) * TILE_ELEMS;
        // write prefetched tile into LDS buffer
        #pragma unroll
        for (int p = 0; p < 2; ++p) {
            int col = sc8 + p * 32;
            *(uint4*)&Ks[buf + srow * KPAD + col] = kreg[p];
            *(uint4*)&Vt[buf + srow * KPAD + col] = vreg[p];
        }
        __syncthreads();
        // issue next tile's global loads (land during compute below)
        if (kt + 1 < SEQ / 64) {
            #pragma unroll
            for (int p = 0; p < 2; ++p) {
                int col = sc8 + p * 32;
                kreg[p] = *(const uint4*)&kb[(size_t)((kt + 1) * 64 + srow) * HD + col];
                vreg[p] = *(const uint4*)&vtb[(size_t)srow * SEQ + (kt + 1) * 64 + col];
            }
        }

        // ---- S = Q K^T ----
        f32x4 s_acc[4];
        #pragma unroll
        for (int nt = 0; nt < 4; ++nt) {
            const unsigned short* kp = &Ks[buf + (nt * 16 + cc) * KPAD + quad * 8];
            bf16x8 kf0 = *(const bf16x8*)kp;
            bf16x8 kf1 = *(const bf16x8*)(kp + 32);
            f32x4 z = {};
            z = __builtin_amdgcn_mfma_f32_16x16x32_bf16(qa0, kf0, z, 0, 0, 0);
            s_acc[nt] = __builtin_amdgcn_mfma_f32_16x16x32_bf16(qa1, kf1, z, 0, 0, 0);
        }

        // ---- pm = exp(S/8); per-lane row-sum accumulation ----
        float pm[4][4];
        #pragma unroll
        for (int nt = 0; nt < 4; ++nt)
            #pragma unroll
            for (int r = 0; r < 4; ++r) {
                pm[nt][r] = __expf(s_acc[nt][r] * 0.125f);
                l_i[r] += pm[nt][r];
            }

        // ---- P: C-layout -> wave-private LDS -> A-layout ----
        unsigned short* pw = &Ps[wave * 16 * KPAD];
        #pragma unroll
        for (int nt = 0; nt < 4; ++nt)
            #pragma unroll
            for (int r = 0; r < 4; ++r)
                pw[(quad * 4 + r) * KPAD + nt * 16 + cc] = f2bf_up(pm[nt][r]);

        const unsigned short* pa = &pw[cc * KPAD + quad * 8];
        bf16x8 pf0 = *(const bf16x8*)pa;
        bf16x8 pf1 = *(const bf16x8*)(pa + 32);

        // ---- O += P V ----
        #pragma unroll
        for (int nt = 0; nt < 4; ++nt) {
            const unsigned short* vp = &Vt[buf + (nt * 16 + cc) * KPAD + quad * 8];
            bf16x8 vf0 = *(const bf16x8*)vp;
            bf16x8 vf1 = *(const bf16x8*)(vp + 32);
            o_acc[nt] = __builtin_amdgcn_mfma_f32_16x16x32_bf16(pf0, vf0, o_acc[nt], 0, 0, 0);
            o_acc[nt] = __builtin_amdgcn_mfma_f32_16x16x32_bf16(pf1, vf1, o_acc[nt], 0, 0, 0);
        }
    }

    float inv_l[4];
    #pragma unroll
    for (int r = 0; r < 4; ++r) {
        float l = l_i[r];
        #pragma unroll
        for (int off = 1; off < 16; off <<= 1)
            l += __shfl_xor(l, off, 64);
        inv_l[r] = 1.0f / l;
    }
    const int b_ = bh >> 4, h = bh & 15;
    #pragma unroll
    for (int nt = 0; nt < 4; ++nt)
        #pragma unroll
        for (int r = 0; r < 4; ++r) {
            int row = qblk * 64 + wave * 16 + quad * 4 + r;
            attn_out[((size_t)(b_ * SEQ + row)) * DMODEL + h * HD + nt * 16 + cc] =
                o_acc[nt][r] * inv_l[r];
        }
}

extern "C" void kernel_launch(void* const* d_in, const int* in_sizes, int n_in,
                              void* d_out, int out_size, void* d_ws, size_t ws_size,
                              hipStream_t stream) {
    const float* src       = (const float*)d_in[0];
    const float* pre_gamma = (const float*)d_in[1];
    const float* pre_beta  = (const float*)d_in[2];
    const float* qkv_w     = (const float*)d_in[3];
    const float* qkv_b     = (const float*)d_in[4];
    const float* an_gamma  = (const float*)d_in[5];
    const float* an_beta   = (const float*)d_in[6];
    const float* fc1_w     = (const float*)d_in[7];
    const float* fc1_b     = (const float*)d_in[8];
    const float* fc2_w     = (const float*)d_in[9];
    const float* fc2_b     = (const float*)d_in[10];
    float* out = (float*)d_out;

    char* ws = (char*)d_ws;
    size_t off = 0;
    auto alloc = [&](size_t bytes) {
        char* p = ws + off;
        off += (bytes + 255) & ~(size_t)255;
        return p;
    };
    float*          x_f   = (float*)alloc((size_t)MROWS * DMODEL * 4);
    unsigned short* x_b   = (unsigned short*)alloc((size_t)MROWS * DMODEL * 2);
    float*          y_f   = (float*)alloc((size_t)MROWS * DMODEL * 4);
    unsigned short* y_b   = (unsigned short*)alloc((size_t)MROWS * DMODEL * 2);
    float*          atf   = (float*)alloc((size_t)MROWS * DMODEL * 4);
    float*          fff   = (float*)alloc((size_t)MROWS * DMODEL * 4);
    unsigned short* qkvb  = (unsigned short*)alloc((size_t)3 * MROWS * DMODEL * 2);
    unsigned short* h_b   = (unsigned short*)alloc((size_t)MROWS * FFN_DIM * 2);
    unsigned short* wqkv  = (unsigned short*)alloc((size_t)3 * DMODEL * DMODEL * 2);
    unsigned short* wfc1  = (unsigned short*)alloc((size_t)FFN_DIM * DMODEL * 2);
    unsigned short* wfc2  = (unsigned short*)alloc((size_t)DMODEL * FFN_DIM * 2);

    unsigned short* vt_b = (unsigned short*)fff;
    float* fc2p0 = fff;            // dead after attn (vt)
    float* fc2p1 = x_f;            // dead after addnorm1
    float* fc2p2 = atf;            // dead after addnorm1
    float* fc2p3 = (float*)qkvb;   // dead after attn

    int n_qkv = 3 * DMODEL * DMODEL / 4;
    int n_fc  = FFN_DIM * DMODEL / 4;
    cvt_f32_bf16<<<dim3((n_qkv + 255) / 256), dim3(256), 0, stream>>>(qkv_w, wqkv, n_qkv);
    cvt_f32_bf16<<<dim3((n_fc + 255) / 256), dim3(256), 0, stream>>>(fc1_w, wfc1, n_fc);
    cvt_f32_bf16<<<dim3((n_fc + 255) / 256), dim3(256), 0, stream>>>(fc2_w, wfc2, n_fc);

    ln_fused<<<dim3(MROWS), dim3(256), 0, stream>>>(src, nullptr, pre_gamma, pre_beta, x_f, x_b);
    gemm_lds<3><<<dim3(3 * DMODEL / 128, MROWS / 128), dim3(256), 0, stream>>>(
        x_b, wqkv, qkv_b, qkvb, nullptr, nullptr, nullptr, MROWS, 3 * DMODEL, DMODEL, DMODEL);
    transpose_v<<<dim3(SEQ / 64, BATCH * NH), dim3(256), 0, stream>>>(
        qkvb + (size_t)2 * BATCH * NH * SEQ * HD, vt_b);
    attn_mfma<<<dim3(SEQ / 64, BATCH * NH), dim3(256), 0, stream>>>(qkvb, vt_b, atf);
    ln_fused<<<dim3(MROWS), dim3(256), 0, stream>>>(atf, x_f, an_gamma, an_beta, y_f, y_b);
    gemm_lds<1><<<dim3(FFN_DIM / 128, MROWS / 128), dim3(256), 0, stream>>>(
        y_b, wfc1, fc1_b, h_b, nullptr, nullptr, nullptr, MROWS, FFN_DIM, DMODEL, DMODEL);
    gemm_lds<4><<<dim3(DMODEL / 128, MROWS / 128, 4), dim3(256), 0, stream>>>(
        h_b, wfc2, nullptr, fc2p0, fc2p1, fc2p2, fc2p3, MROWS, DMODEL, FFN_DIM, 1024);
    ln_fc2<<<dim3(MROWS), dim3(256), 0, stream>>>(
        fc2p0, fc2p1, fc2p2, fc2p3, fc2_b, y_f, an_gamma, an_beta, out);
}

// Round 7
// 393.959 us; speedup vs baseline: 1.1204x; 1.1204x over previous
//
#include <hip/hip_runtime.h>
#include <hip/hip_bf16.h>
#include <math.h>

#define DMODEL 1024
#define NH 16
#define HD 64
#define SEQ 2048
#define BATCH 2
#define MROWS (BATCH * SEQ)   // 4096
#define FFN_DIM 4096

using bf16x8 = __attribute__((ext_vector_type(8))) __bf16;
using f32x4  = __attribute__((ext_vector_type(4))) float;

typedef const __attribute__((address_space(1))) unsigned char* gas_t;
typedef __attribute__((address_space(3))) unsigned char* las_t;

__device__ inline unsigned short f2bf(float f) {
    unsigned int u = __builtin_bit_cast(unsigned int, f);
    u += 0x7fffu + ((u >> 16) & 1u);   // round-to-nearest-even
    return (unsigned short)(u >> 16);
}
// round-half-up — fine for positive P in (0,1]; 2 VALU ops instead of 4
__device__ inline unsigned short f2bf_up(float f) {
    unsigned int u = __builtin_bit_cast(unsigned int, f);
    return (unsigned short)((u + 0x8000u) >> 16);
}
__device__ inline float bf2f(unsigned short u) {
    unsigned int v = ((unsigned int)u) << 16;
    return __builtin_bit_cast(float, v);
}

// ---------------- fp32 -> bf16 conversion, all 3 weight tensors in one launch ----------------
__global__ void cvt_all(const float* __restrict__ a, unsigned short* __restrict__ oa, int na4,
                        const float* __restrict__ b, unsigned short* __restrict__ ob, int nb4,
                        const float* __restrict__ c, unsigned short* __restrict__ oc, int nc4) {
    int i = blockIdx.x * blockDim.x + threadIdx.x;
    const float* src; unsigned short* dst; int j;
    if (i < na4)                { src = a; dst = oa; j = i; }
    else if (i < na4 + nb4)     { src = b; dst = ob; j = i - na4; }
    else if (i < na4 + nb4 + nc4) { src = c; dst = oc; j = i - na4 - nb4; }
    else return;
    float4 v = ((const float4*)src)[j];
    ushort4 o;
    o.x = f2bf(v.x); o.y = f2bf(v.y); o.z = f2bf(v.z); o.w = f2bf(v.w);
    ((ushort4*)dst)[j] = o;
}

// ---------------- fused (residual-add +) LayerNorm ----------------
__global__ __launch_bounds__(256) void ln_fused(
        const float* __restrict__ a, const float* __restrict__ b,
        const float* __restrict__ gamma, const float* __restrict__ beta,
        float* __restrict__ out_f, unsigned short* __restrict__ out_b) {
    int row = blockIdx.x;
    int t = threadIdx.x;
    float4 v = ((const float4*)(a + (size_t)row * DMODEL))[t];
    if (b) {
        float4 w = ((const float4*)(b + (size_t)row * DMODEL))[t];
        v.x += w.x; v.y += w.y; v.z += w.z; v.w += w.w;
    }
    float s  = v.x + v.y + v.z + v.w;
    float s2 = v.x * v.x + v.y * v.y + v.z * v.z + v.w * v.w;
    #pragma unroll
    for (int off = 32; off > 0; off >>= 1) {
        s  += __shfl_xor(s,  off, 64);
        s2 += __shfl_xor(s2, off, 64);
    }
    __shared__ float red[8];
    int wave = t >> 6, lane = t & 63;
    if (lane == 0) { red[wave] = s; red[4 + wave] = s2; }
    __syncthreads();
    float tot  = red[0] + red[1] + red[2] + red[3];
    float tot2 = red[4] + red[5] + red[6] + red[7];
    float mu   = tot * (1.0f / DMODEL);
    float var  = tot2 * (1.0f / DMODEL) - mu * mu;
    float rstd = rsqrtf(var + 1e-5f);
    float4 g  = ((const float4*)gamma)[t];
    float4 be = ((const float4*)beta)[t];
    float4 o;
    o.x = (v.x - mu) * rstd * g.x + be.x;
    o.y = (v.y - mu) * rstd * g.y + be.y;
    o.z = (v.z - mu) * rstd * g.z + be.z;
    o.w = (v.w - mu) * rstd * g.w + be.w;
    if (out_f) ((float4*)(out_f + (size_t)row * DMODEL))[t] = o;
    if (out_b) {
        ushort4 ob;
        ob.x = f2bf(o.x); ob.y = f2bf(o.y); ob.z = f2bf(o.z); ob.w = f2bf(o.w);
        ((ushort4*)(out_b + (size_t)row * DMODEL))[t] = ob;
    }
}

// ---------------- AddNorm fused with split-K reduction (FC2 epilogue) ----------------
// out = LN( (p0+p1+p2+p3) + fc2_bias + residual ); partials are bf16
__global__ __launch_bounds__(256) void ln_fc2(
        const unsigned short* __restrict__ p0, const unsigned short* __restrict__ p1,
        const unsigned short* __restrict__ p2, const unsigned short* __restrict__ p3,
        const float* __restrict__ bias, const float* __restrict__ resid,
        const float* __restrict__ gamma, const float* __restrict__ beta,
        float* __restrict__ out_f) {
    int row = blockIdx.x;
    int t = threadIdx.x;
    size_t base = (size_t)row * DMODEL;
    ushort4 u0 = ((const ushort4*)(p0 + base))[t];
    ushort4 u1 = ((const ushort4*)(p1 + base))[t];
    ushort4 u2 = ((const ushort4*)(p2 + base))[t];
    ushort4 u3 = ((const ushort4*)(p3 + base))[t];
    float4 bb = ((const float4*)bias)[t];
    float4 rr = ((const float4*)(resid + base))[t];
    float4 v;
    v.x = bf2f(u0.x) + bf2f(u1.x) + bf2f(u2.x) + bf2f(u3.x) + bb.x + rr.x;
    v.y = bf2f(u0.y) + bf2f(u1.y) + bf2f(u2.y) + bf2f(u3.y) + bb.y + rr.y;
    v.z = bf2f(u0.z) + bf2f(u1.z) + bf2f(u2.z) + bf2f(u3.z) + bb.z + rr.z;
    v.w = bf2f(u0.w) + bf2f(u1.w) + bf2f(u2.w) + bf2f(u3.w) + bb.w + rr.w;

    float s  = v.x + v.y + v.z + v.w;
    float s2 = v.x * v.x + v.y * v.y + v.z * v.z + v.w * v.w;
    #pragma unroll
    for (int off = 32; off > 0; off >>= 1) {
        s  += __shfl_xor(s,  off, 64);
        s2 += __shfl_xor(s2, off, 64);
    }
    __shared__ float red[8];
    int wave = t >> 6, lane = t & 63;
    if (lane == 0) { red[wave] = s; red[4 + wave] = s2; }
    __syncthreads();
    float tot  = red[0] + red[1] + red[2] + red[3];
    float tot2 = red[4] + red[5] + red[6] + red[7];
    float mu   = tot * (1.0f / DMODEL);
    float var  = tot2 * (1.0f / DMODEL) - mu * mu;
    float rstd = rsqrtf(var + 1e-5f);
    float4 g  = ((const float4*)gamma)[t];
    float4 be = ((const float4*)beta)[t];
    float4 o;
    o.x = (v.x - mu) * rstd * g.x + be.x;
    o.y = (v.y - mu) * rstd * g.y + be.y;
    o.z = (v.z - mu) * rstd * g.z + be.z;
    o.w = (v.w - mu) * rstd * g.w + be.w;
    ((float4*)(out_f + base))[t] = o;
}

// ---------------- m97-style LDS-staged bf16 NT GEMM ----------------
// MODE 1: bias+GELU->bf16  MODE 2: bias->f32  MODE 3: qkv scatter bf16 (q pre-scaled by 1/8)
// MODE 4: split-K bf16 partial (no bias)
template <int MODE>
__global__ __launch_bounds__(256) void gemm_lds(
        const unsigned short* __restrict__ A,
        const unsigned short* __restrict__ Bw,
        const float* __restrict__ bias,
        void* __restrict__ out, unsigned short* __restrict__ q1,
        unsigned short* __restrict__ q2, unsigned short* __restrict__ q3,
        int M, int N, int K, int KC) {
    __shared__ unsigned short As[128 * 32];
    __shared__ unsigned short Bs[128 * 32];

    const int tid  = threadIdx.x;
    const int wave = tid >> 6;
    const int lane = tid & 63;
    const int quad = lane >> 4;
    const int cc   = lane & 15;
    const int bn = blockIdx.x * 128;
    const int bm = blockIdx.y * 128;

    const unsigned short* Ab = A  + (size_t)bm * K;
    const unsigned short* Bb = Bw + (size_t)bn * K;

    const int srow0 = tid >> 2;
    const int ssg   = tid & 3;
    const int rsg = quad ^ ((cc >> 1) & 3);
    const int wm = (wave >> 1) * 64;
    const int wn = (wave & 1) * 64;

    const int kbeg = blockIdx.z * KC;
    const int kend = kbeg + KC;

    f32x4 acc[4][4] = {};

    for (int k0 = kbeg; k0 < kend; k0 += 32) {
        #pragma unroll
        for (int i = 0; i < 2; ++i) {
            int row = i * 64 + srow0;
            int g   = ssg ^ ((row >> 1) & 3);
            const unsigned short* ga = Ab + (size_t)row * K + k0 + g * 8;
            const unsigned short* gb = Bb + (size_t)row * K + k0 + g * 8;
            unsigned short* la = &As[i * 2048 + wave * 512];
            unsigned short* lb = &Bs[i * 2048 + wave * 512];
            __builtin_amdgcn_global_load_lds((gas_t)(const void*)ga, (las_t)(void*)la, 16, 0, 0);
            __builtin_amdgcn_global_load_lds((gas_t)(const void*)gb, (las_t)(void*)lb, 16, 0, 0);
        }
        __syncthreads();

        bf16x8 af[4], bf[4];
        #pragma unroll
        for (int mt = 0; mt < 4; ++mt)
            af[mt] = *(const bf16x8*)&As[(wm + mt * 16 + cc) * 32 + rsg * 8];
        #pragma unroll
        for (int nt = 0; nt < 4; ++nt)
            bf[nt] = *(const bf16x8*)&Bs[(wn + nt * 16 + cc) * 32 + rsg * 8];

        #pragma unroll
        for (int mt = 0; mt < 4; ++mt)
            #pragma unroll
            for (int nt = 0; nt < 4; ++nt)
                acc[mt][nt] = __builtin_amdgcn_mfma_f32_16x16x32_bf16(
                    af[mt], bf[nt], acc[mt][nt], 0, 0, 0);

        __syncthreads();
    }

    unsigned short* outp_b = (unsigned short*)out;
    if constexpr (MODE == 4) {
        outp_b = (blockIdx.z == 0) ? (unsigned short*)out
               : (blockIdx.z == 1) ? q1
               : (blockIdx.z == 2) ? q2 : q3;
    }

    #pragma unroll
    for (int mt = 0; mt < 4; ++mt)
        #pragma unroll
        for (int nt = 0; nt < 4; ++nt)
            #pragma unroll
            for (int r = 0; r < 4; ++r) {
                int m = bm + wm + mt * 16 + quad * 4 + r;
                int n = bn + wn + nt * 16 + cc;
                if constexpr (MODE == 4) {
                    outp_b[(size_t)m * N + n] = f2bf(acc[mt][nt][r]);
                    continue;
                }
                float v = acc[mt][nt][r] + bias[n];
                if constexpr (MODE == 1)
                    v = 0.5f * v * (1.0f + erff(v * 0.70710678118654752f));
                if constexpr (MODE == 2) {
                    ((float*)out)[(size_t)m * N + n] = v;
                } else if constexpr (MODE == 3) {
                    int b_ = m >> 11, srow = m & 2047;
                    int which = n >> 10, rem = n & 1023;
                    int h = rem >> 6, d = rem & 63;
                    if (which == 0) v *= 0.125f;   // fold 1/sqrt(HD) into Q
                    size_t idx = ((((size_t)which * BATCH + b_) * NH + h) * SEQ + srow) * HD + d;
                    ((unsigned short*)out)[idx] = f2bf(v);
                } else {
                    ((unsigned short*)out)[(size_t)m * N + n] = f2bf(v);
                }
            }
}

// ---------------- V transpose: [bh][s][hd] -> [bh][hd][s] ----------------
__global__ __launch_bounds__(256) void transpose_v(
        const unsigned short* __restrict__ vsrc, unsigned short* __restrict__ vt) {
    __shared__ unsigned short Ls[64 * 72];
    const int t = threadIdx.x;
    const int s0 = blockIdx.x * 64;
    const int bh = blockIdx.y;
    const unsigned short* in = vsrc + (size_t)bh * SEQ * HD;
    unsigned short* outp = vt + (size_t)bh * SEQ * HD;

    const int row = t >> 2;
    const int c8  = (t & 3) * 8;
    #pragma unroll
    for (int p = 0; p < 2; ++p)
        *(uint4*)&Ls[row * 72 + c8 + p * 32] =
            *(const uint4*)&in[(size_t)(s0 + row) * HD + c8 + p * 32];
    __syncthreads();

    const int hd = t >> 2;
    #pragma unroll
    for (int p = 0; p < 2; ++p) {
        unsigned short tmp[8];
        #pragma unroll
        for (int j = 0; j < 8; ++j)
            tmp[j] = Ls[(c8 + p * 32 + j) * 72 + hd];
        *(uint4*)&outp[(size_t)hd * SEQ + s0 + c8 + p * 32] = *(uint4*)tmp;
    }
}

// ---------------- MFMA flash attention (R5 structure — single-buffered) ----------------
// Q pre-scaled by 1/8 at QKV epilogue; fixed-max softmax; deferred row-sum.
#define KPAD 72
__global__ __launch_bounds__(256) void attn_mfma(
        const unsigned short* __restrict__ qkv,
        const unsigned short* __restrict__ vt, float* __restrict__ attn_out) {
    const int tid  = threadIdx.x;
    const int wave = tid >> 6;
    const int lane = tid & 63;
    const int quad = lane >> 4;
    const int cc   = lane & 15;
    const int qblk = blockIdx.x;
    const int bh   = blockIdx.y;

    const size_t headsz = (size_t)SEQ * HD;
    const unsigned short* qb  = qkv + (size_t)bh * headsz;
    const unsigned short* kb  = qkv + ((size_t)BATCH * NH + bh) * headsz;
    const unsigned short* vtb = vt + (size_t)bh * headsz;

    __shared__ unsigned short Ks[64 * KPAD];
    __shared__ unsigned short Vt[64 * KPAD];
    __shared__ unsigned short Ps[4 * 16 * KPAD];

    const int qrow = qblk * 64 + wave * 16 + cc;
    const unsigned short* qp = qb + (size_t)qrow * HD + quad * 8;
    bf16x8 qa0 = *(const bf16x8*)qp;
    bf16x8 qa1 = *(const bf16x8*)(qp + 32);

    f32x4 o_acc[4] = {};
    float l_i[4] = {0.f, 0.f, 0.f, 0.f};

    const int srow = wave * 16 + (lane >> 2);
    const int sc8  = (lane & 3) * 8;

    for (int kt = 0; kt < SEQ / 64; ++kt) {
        __syncthreads();
        #pragma unroll
        for (int p = 0; p < 2; ++p) {
            int col = sc8 + p * 32;
            *(uint4*)&Ks[srow * KPAD + col] =
                *(const uint4*)&kb[(size_t)(kt * 64 + srow) * HD + col];
            *(uint4*)&Vt[srow * KPAD + col] =
                *(const uint4*)&vtb[(size_t)srow * SEQ + kt * 64 + col];
        }
        __syncthreads();

        f32x4 s_acc[4];
        #pragma unroll
        for (int nt = 0; nt < 4; ++nt) {
            const unsigned short* kp = &Ks[(nt * 16 + cc) * KPAD + quad * 8];
            bf16x8 kf0 = *(const bf16x8*)kp;
            bf16x8 kf1 = *(const bf16x8*)(kp + 32);
            f32x4 z = {};
            z = __builtin_amdgcn_mfma_f32_16x16x32_bf16(qa0, kf0, z, 0, 0, 0);
            s_acc[nt] = __builtin_amdgcn_mfma_f32_16x16x32_bf16(qa1, kf1, z, 0, 0, 0);
        }

        float pm[4][4];
        #pragma unroll
        for (int nt = 0; nt < 4; ++nt)
            #pragma unroll
            for (int r = 0; r < 4; ++r) {
                pm[nt][r] = __expf(s_acc[nt][r]);
                l_i[r] += pm[nt][r];
            }

        unsigned short* pw = &Ps[wave * 16 * KPAD];
        #pragma unroll
        for (int nt = 0; nt < 4; ++nt)
            #pragma unroll
            for (int r = 0; r < 4; ++r)
                pw[(quad * 4 + r) * KPAD + nt * 16 + cc] = f2bf_up(pm[nt][r]);

        const unsigned short* pa = &pw[cc * KPAD + quad * 8];
        bf16x8 pf0 = *(const bf16x8*)pa;
        bf16x8 pf1 = *(const bf16x8*)(pa + 32);

        #pragma unroll
        for (int nt = 0; nt < 4; ++nt) {
            const unsigned short* vp = &Vt[(nt * 16 + cc) * KPAD + quad * 8];
            bf16x8 vf0 = *(const bf16x8*)vp;
            bf16x8 vf1 = *(const bf16x8*)(vp + 32);
            o_acc[nt] = __builtin_amdgcn_mfma_f32_16x16x32_bf16(pf0, vf0, o_acc[nt], 0, 0, 0);
            o_acc[nt] = __builtin_amdgcn_mfma_f32_16x16x32_bf16(pf1, vf1, o_acc[nt], 0, 0, 0);
        }
    }

    float inv_l[4];
    #pragma unroll
    for (int r = 0; r < 4; ++r) {
        float l = l_i[r];
        #pragma unroll
        for (int off = 1; off < 16; off <<= 1)
            l += __shfl_xor(l, off, 64);
        inv_l[r] = 1.0f / l;
    }
    const int b_ = bh >> 4, h = bh & 15;
    #pragma unroll
    for (int nt = 0; nt < 4; ++nt)
        #pragma unroll
        for (int r = 0; r < 4; ++r) {
            int row = qblk * 64 + wave * 16 + quad * 4 + r;
            attn_out[((size_t)(b_ * SEQ + row)) * DMODEL + h * HD + nt * 16 + cc] =
                o_acc[nt][r] * inv_l[r];
        }
}

extern "C" void kernel_launch(void* const* d_in, const int* in_sizes, int n_in,
                              void* d_out, int out_size, void* d_ws, size_t ws_size,
                              hipStream_t stream) {
    const float* src       = (const float*)d_in[0];
    const float* pre_gamma = (const float*)d_in[1];
    const float* pre_beta  = (const float*)d_in[2];
    const float* qkv_w     = (const float*)d_in[3];
    const float* qkv_b     = (const float*)d_in[4];
    const float* an_gamma  = (const float*)d_in[5];
    const float* an_beta   = (const float*)d_in[6];
    const float* fc1_w     = (const float*)d_in[7];
    const float* fc1_b     = (const float*)d_in[8];
    const float* fc2_w     = (const float*)d_in[9];
    const float* fc2_b     = (const float*)d_in[10];
    float* out = (float*)d_out;

    char* ws = (char*)d_ws;
    size_t off = 0;
    auto alloc = [&](size_t bytes) {
        char* p = ws + off;
        off += (bytes + 255) & ~(size_t)255;
        return p;
    };
    float*          x_f   = (float*)alloc((size_t)MROWS * DMODEL * 4);   // dead after addnorm1
    unsigned short* x_b   = (unsigned short*)alloc((size_t)MROWS * DMODEL * 2);
    float*          y_f   = (float*)alloc((size_t)MROWS * DMODEL * 4);
    unsigned short* y_b   = (unsigned short*)alloc((size_t)MROWS * DMODEL * 2);
    float*          atf   = (float*)alloc((size_t)MROWS * DMODEL * 4);   // dead after addnorm1
    float*          fff   = (float*)alloc((size_t)MROWS * DMODEL * 4);   // vt alias; dead after attn
    unsigned short* qkvb  = (unsigned short*)alloc((size_t)3 * MROWS * DMODEL * 2); // dead after attn
    unsigned short* h_b   = (unsigned short*)alloc((size_t)MROWS * FFN_DIM * 2);
    unsigned short* wqkv  = (unsigned short*)alloc((size_t)3 * DMODEL * DMODEL * 2);
    unsigned short* wfc1  = (unsigned short*)alloc((size_t)FFN_DIM * DMODEL * 2);
    unsigned short* wfc2  = (unsigned short*)alloc((size_t)DMODEL * FFN_DIM * 2);

    unsigned short* vt_b = (unsigned short*)fff;
    // fc2 split-K bf16 partial buffers (8 MB each), aliased onto dead regions:
    unsigned short* fc2p0 = (unsigned short*)fff;
    unsigned short* fc2p1 = (unsigned short*)x_f;
    unsigned short* fc2p2 = (unsigned short*)atf;
    unsigned short* fc2p3 = (unsigned short*)qkvb;

    int n_qkv = 3 * DMODEL * DMODEL / 4;
    int n_fc  = FFN_DIM * DMODEL / 4;
    int n_tot = n_qkv + 2 * n_fc;
    cvt_all<<<dim3((n_tot + 255) / 256), dim3(256), 0, stream>>>(
        qkv_w, wqkv, n_qkv, fc1_w, wfc1, n_fc, fc2_w, wfc2, n_fc);

    ln_fused<<<dim3(MROWS), dim3(256), 0, stream>>>(src, nullptr, pre_gamma, pre_beta, x_f, x_b);
    gemm_lds<3><<<dim3(3 * DMODEL / 128, MROWS / 128), dim3(256), 0, stream>>>(
        x_b, wqkv, qkv_b, qkvb, nullptr, nullptr, nullptr, MROWS, 3 * DMODEL, DMODEL, DMODEL);
    transpose_v<<<dim3(SEQ / 64, BATCH * NH), dim3(256), 0, stream>>>(
        qkvb + (size_t)2 * BATCH * NH * SEQ * HD, vt_b);
    attn_mfma<<<dim3(SEQ / 64, BATCH * NH), dim3(256), 0, stream>>>(qkvb, vt_b, atf);
    ln_fused<<<dim3(MROWS), dim3(256), 0, stream>>>(atf, x_f, an_gamma, an_beta, y_f, y_b);
    gemm_lds<1><<<dim3(FFN_DIM / 128, MROWS / 128), dim3(256), 0, stream>>>(
        y_b, wfc1, fc1_b, h_b, nullptr, nullptr, nullptr, MROWS, FFN_DIM, DMODEL, DMODEL);
    gemm_lds<4><<<dim3(DMODEL / 128, MROWS / 128, 4), dim3(256), 0, stream>>>(
        h_b, wfc2, nullptr, fc2p0, fc2p1, fc2p2, fc2p3, MROWS, DMODEL, FFN_DIM, 1024);
    ln_fc2<<<dim3(MROWS), dim3(256), 0, stream>>>(
        fc2p0, fc2p1, fc2p2, fc2p3, fc2_b, y_f, an_gamma, an_beta, out);
}